// Round 6
// baseline (318.629 us; speedup 1.0000x reference)
//
#include <hip/hip_runtime.h>
#include <hip/hip_bf16.h>

#define FEATSZ 2048
#define HIDSZ  1024
#define ATTSZ  512
#define BATCH  64
#define FEATN  512

typedef float  f32x4  __attribute__((ext_vector_type(4)));
typedef __bf16 bf16x8 __attribute__((ext_vector_type(8)));

__device__ __forceinline__ unsigned short f2bf(float f) {
    union { float f; unsigned int u; } x; x.f = f;
    unsigned int u = x.u;
    return (unsigned short)((u + 0x7fffu + ((u >> 16) & 1u)) >> 16);
}

// ---------------- K0a: h = key @ wh_w.T + wh_b  (64 x 512) ----------------
__global__ void k_h(const float* __restrict__ key, const float* __restrict__ wh_w,
                    const float* __restrict__ wh_b, float* __restrict__ h) {
    const int b = blockIdx.y;
    const int ac = blockIdx.x;
    const int t = threadIdx.x;         // 256
    const int lane = t & 63, wv = t >> 6;
    float k16[16];
    const float* kb = key + b * HIDSZ;
#pragma unroll
    for (int j = 0; j < 16; ++j) k16[j] = kb[lane + 64 * j];
#pragma unroll 1
    for (int i = 0; i < 16; ++i) {
        int a = ac * 64 + wv * 16 + i;
        const float* wr = wh_w + (size_t)a * HIDSZ;
        float s = 0.f;
#pragma unroll
        for (int j = 0; j < 16; ++j) s += k16[j] * wr[lane + 64 * j];
#pragma unroll
        for (int d = 32; d; d >>= 1) s += __shfl_xor(s, d);
        if (lane == 0) h[b * ATTSZ + a] = s + wh_b[a];
    }
}

// ------- K0b: convert wv_w (512x2048 f32) -> bf16 in MFMA-fragment order -------
// frag (kk, CF) = 1024B at (kk*32+CF)*1024; lane l holds 16B (8 bf16) at +l*16.
__global__ void k_wvcvt(const float* __restrict__ wv_w, unsigned short* __restrict__ wvb) {
    int idx = blockIdx.x * 256 + threadIdx.x;       // < 512*2048
    int a = idx >> 11, k = idx & 2047;
    int CF = a >> 4, c = a & 15, ks = k >> 5, kin = k & 31;
    int lane = c + ((kin >> 3) << 4);
    int dst = ((ks * 32 + CF) * 64 + lane) * 8 + (kin & 7);
    wvb[dst] = f2bf(wv_w[idx]);
}

// ---------------- K1: fused GEMM(feats, wv^T) + tanh·wa -> partial scores ----------
// 1024 blocks (4/CU), 256 thr = 4 waves (one per SIMD -> cross-block latency hiding).
// Block tile 128 rows x 128 cols (nc = bx&3 selects col-quarter), BK=32, 64 iters.
// A: fp32 glb -> reg -> bf16 cvt -> padded LDS [128][36]; B: global_load_lds direct
// from frag-ordered wvb (8KB/iter, LDS-linear). 16 MFMA + 8 ds_read_b128 /wave/iter.
__global__ __launch_bounds__(256, 4) void k_scores(
        const float* __restrict__ feats, const unsigned short* __restrict__ wvb,
        const float* __restrict__ h, const float* __restrict__ wv_b,
        const float* __restrict__ wa, float* __restrict__ part_sc) {
    __shared__ __align__(16) __bf16 Alds[2][128 * 36];   // 9216 B x2 (pad 4 bf16/row)
    __shared__ __align__(16) char  Blds[2][8192];
    __shared__ float scp[2][128];

    const int t = threadIdx.x, lane = t & 63, w = t >> 6;
    const int wr = w >> 1, wc = w & 1;
    const int mb = blockIdx.x >> 2, nc = blockIdx.x & 3;
    const int m0 = mb * 128;
    const int b = mb >> 2;                         // batch (4 m-blocks per batch)

    // ---- A staging addresses: thread -> row sr=t>>1, k-half hk=t&1 (16 f32 = one 64B)
    const int sr = t >> 1, hk = t & 1;
    const float* gA = feats + (size_t)(m0 + sr) * FEATSZ + hk * 16;
    __bf16* wA = &Alds[0][0] + sr * 36 + hk * 16;  // +buf*4608 elements

    // ---- B staging: wave w instr i covers 1024B chunk (w*2+i)
    const char* gB = (const char*)wvb + (size_t)nc * 8 * 1024 + (w * 2) * 1024 + lane * 16;

    // ---- frag read offsets
    const int arow = wr * 64 + (lane & 15);
    const int aoff = (lane >> 4) * 16;             // byte offset within row
    const char* bbase = &Blds[0][0] + (wc * 4) * 1024 + lane * 16;

    f32x4 acc[4][4];
#pragma unroll
    for (int m = 0; m < 4; ++m)
#pragma unroll
        for (int cf = 0; cf < 4; ++cf) acc[m][cf] = (f32x4)0.0f;

    // ---- prologue: stage it=0 into buf 0
    {
        f32x4 s0 = *(const f32x4*)(gA);
        f32x4 s1 = *(const f32x4*)(gA + 4);
        f32x4 s2 = *(const f32x4*)(gA + 8);
        f32x4 s3 = *(const f32x4*)(gA + 12);
#pragma unroll
        for (int i = 0; i < 2; ++i)
            __builtin_amdgcn_global_load_lds(
                (const __attribute__((address_space(1))) void*)(gB + i * 1024),
                (__attribute__((address_space(3))) void*)(&Blds[0][0] + (w * 2 + i) * 1024 + lane * 16),
                16, 0, 0);
        bf16x8 a0, a1;
        a0[0]=(__bf16)s0[0]; a0[1]=(__bf16)s0[1]; a0[2]=(__bf16)s0[2]; a0[3]=(__bf16)s0[3];
        a0[4]=(__bf16)s1[0]; a0[5]=(__bf16)s1[1]; a0[6]=(__bf16)s1[2]; a0[7]=(__bf16)s1[3];
        a1[0]=(__bf16)s2[0]; a1[1]=(__bf16)s2[1]; a1[2]=(__bf16)s2[2]; a1[3]=(__bf16)s2[3];
        a1[4]=(__bf16)s3[0]; a1[5]=(__bf16)s3[1]; a1[6]=(__bf16)s3[2]; a1[7]=(__bf16)s3[3];
        *(bf16x8*)__builtin_assume_aligned(wA, 4) = a0;
        *(bf16x8*)__builtin_assume_aligned(wA + 8, 4) = a1;
    }
    __syncthreads();

#pragma unroll 1
    for (int it = 0; it < 64; ++it) {
        const int buf = it & 1;
        f32x4 s0, s1, s2, s3;
        if (it < 63) {
            const float* g = gA + (it + 1) * 32;
            s0 = *(const f32x4*)(g);
            s1 = *(const f32x4*)(g + 4);
            s2 = *(const f32x4*)(g + 8);
            s3 = *(const f32x4*)(g + 12);
            const char* gb = gB + (size_t)(it + 1) * 32768;
#pragma unroll
            for (int i = 0; i < 2; ++i)
                __builtin_amdgcn_global_load_lds(
                    (const __attribute__((address_space(1))) void*)(gb + i * 1024),
                    (__attribute__((address_space(3))) void*)(&Blds[buf ^ 1][0] + (w * 2 + i) * 1024 + lane * 16),
                    16, 0, 0);
        }
        // ---- compute on buf
        const __bf16* ar = &Alds[buf][0];
        const char* br = bbase + buf * (int)sizeof(Blds[0]) * 0 + (buf ? (int)(sizeof(Blds[0])) : 0) * 0;
        // (buf select via explicit pointers below)
        const char* bsel = &Blds[buf][0] + (wc * 4) * 1024 + lane * 16;
        bf16x8 bf_[4];
#pragma unroll
        for (int cf = 0; cf < 4; ++cf)
            bf_[cf] = *(const bf16x8*)__builtin_assume_aligned(bsel + cf * 1024, 16);
        bf16x8 af_[4];
#pragma unroll
        for (int m = 0; m < 4; ++m)
            af_[m] = *(const bf16x8*)__builtin_assume_aligned(
                         (const char*)(ar + (arow + m * 16) * 36) + aoff, 4);
        __builtin_amdgcn_s_setprio(1);
#pragma unroll
        for (int m = 0; m < 4; ++m)
#pragma unroll
            for (int cf = 0; cf < 4; ++cf)
                acc[m][cf] = __builtin_amdgcn_mfma_f32_16x16x32_bf16(af_[m], bf_[cf], acc[m][cf], 0, 0, 0);
        __builtin_amdgcn_s_setprio(0);
        if (it < 63) {
            bf16x8 a0, a1;
            a0[0]=(__bf16)s0[0]; a0[1]=(__bf16)s0[1]; a0[2]=(__bf16)s0[2]; a0[3]=(__bf16)s0[3];
            a0[4]=(__bf16)s1[0]; a0[5]=(__bf16)s1[1]; a0[6]=(__bf16)s1[2]; a0[7]=(__bf16)s1[3];
            a1[0]=(__bf16)s2[0]; a1[1]=(__bf16)s2[1]; a1[2]=(__bf16)s2[2]; a1[3]=(__bf16)s2[3];
            a1[4]=(__bf16)s3[0]; a1[5]=(__bf16)s3[1]; a1[6]=(__bf16)s3[2]; a1[7]=(__bf16)s3[3];
            __bf16* wd = wA + (buf ^ 1) * (128 * 36);
            *(bf16x8*)__builtin_assume_aligned(wd, 4) = a0;
            *(bf16x8*)__builtin_assume_aligned(wd + 8, 4) = a1;
        }
        __syncthreads();
    }

    // ---- epilogue: partial score = sum over this block's 128 cols
    const int c16 = lane & 15, q4 = lane >> 4;
    float hreg[4], wreg[4];
#pragma unroll
    for (int cf = 0; cf < 4; ++cf) {
        int a = nc * 128 + wc * 64 + cf * 16 + c16;
        hreg[cf] = h[b * ATTSZ + a] + wv_b[a];
        wreg[cf] = wa[a];
    }
    float pv[4][4];
#pragma unroll
    for (int m = 0; m < 4; ++m)
#pragma unroll
        for (int j = 0; j < 4; ++j) pv[m][j] = 0.f;
#pragma unroll
    for (int m = 0; m < 4; ++m)
#pragma unroll
        for (int cf = 0; cf < 4; ++cf)
#pragma unroll
            for (int j = 0; j < 4; ++j)
                pv[m][j] += tanhf(acc[m][cf][j] + hreg[cf]) * wreg[cf];
#pragma unroll
    for (int m = 0; m < 4; ++m)
#pragma unroll
        for (int j = 0; j < 4; ++j) {
            float v = pv[m][j];
            v += __shfl_xor(v, 1); v += __shfl_xor(v, 2);
            v += __shfl_xor(v, 4); v += __shfl_xor(v, 8);
            pv[m][j] = v;
        }
    if (c16 == 0) {
#pragma unroll
        for (int m = 0; m < 4; ++m)
#pragma unroll
            for (int j = 0; j < 4; ++j)
                scp[wc][wr * 64 + m * 16 + q4 * 4 + j] = pv[m][j];
    }
    __syncthreads();
    if (t < 128)
        part_sc[nc * (BATCH * FEATN) + m0 + t] = scp[0][t] + scp[1][t];
}

// ---------------- K2: softmax over N=512 per batch (sums 4 col-partials) --------
__global__ void k_softmax(const float* __restrict__ part_sc, float* __restrict__ alpha) {
    __shared__ float red[16];
    const int b = blockIdx.x, t = threadIdx.x;     // 512 threads
    const int lane = t & 63, w = t >> 6;
    const int r = b * FEATN + t;
    float s = part_sc[r] + part_sc[BATCH * FEATN + r]
            + part_sc[2 * BATCH * FEATN + r] + part_sc[3 * BATCH * FEATN + r];
    float m = s;
#pragma unroll
    for (int d = 32; d; d >>= 1) m = fmaxf(m, __shfl_xor(m, d));
    if (lane == 0) red[w] = m;
    __syncthreads();
    if (t == 0) {
        float mm = red[0];
        for (int i = 1; i < 8; ++i) mm = fmaxf(mm, red[i]);
        red[8] = mm;
    }
    __syncthreads();
    float e = __expf(s - red[8]);
    float sum = e;
#pragma unroll
    for (int d = 32; d; d >>= 1) sum += __shfl_xor(sum, d);
    if (lane == 0) red[w] = sum;
    __syncthreads();
    if (t == 0) {
        float ss = 0.f;
        for (int i = 0; i < 8; ++i) ss += red[i];
        red[9] = 1.0f / ss;
    }
    __syncthreads();
    alpha[b * FEATN + t] = e * red[9];
}

// ---------------- K3a: partial att_feats over n-slices ----------------
__global__ void k_att_part(const float* __restrict__ feats, const float* __restrict__ alpha,
                           float* __restrict__ part) {
    const int b = blockIdx.x, fc = blockIdx.y, ns = blockIdx.z, t = threadIdx.x;
    const int f0 = fc * 1024 + t * 4;
    const float* fp = feats + (size_t)(b * FEATN + ns * 128) * FEATSZ + f0;
    const float* al = alpha + b * FEATN + ns * 128;
    float4 acc = {0.f, 0.f, 0.f, 0.f};
#pragma unroll 4
    for (int i = 0; i < 128; ++i) {
        float a = al[i];
        float4 v = *(const float4*)(fp + (size_t)i * FEATSZ);
        acc.x += a * v.x; acc.y += a * v.y; acc.z += a * v.z; acc.w += a * v.w;
    }
    *(float4*)(part + ((size_t)ns * BATCH + b) * FEATSZ + f0) = acc;
}

// ---------------- K3b: reduce 4 partials -> att_feats ----------------
__global__ void k_att_red(const float* __restrict__ part, float* __restrict__ out) {
    const int idx = (blockIdx.x * 256 + threadIdx.x) * 4;   // < 131072
    float4 s = *(const float4*)(part + idx);
#pragma unroll
    for (int z = 1; z < 4; ++z) {
        float4 v = *(const float4*)(part + (size_t)z * (BATCH * FEATSZ) + idx);
        s.x += v.x; s.y += v.y; s.z += v.z; s.w += v.w;
    }
    *(float4*)(out + idx) = s;
}

extern "C" void kernel_launch(void* const* d_in, const int* in_sizes, int n_in,
                              void* d_out, int out_size, void* d_ws, size_t ws_size,
                              hipStream_t stream) {
    const float* feats = (const float*)d_in[0];
    const float* key   = (const float*)d_in[1];
    const float* wh_w  = (const float*)d_in[2];
    const float* wh_b  = (const float*)d_in[3];
    const float* wv_w  = (const float*)d_in[4];
    const float* wv_b  = (const float*)d_in[5];
    const float* wa_w  = (const float*)d_in[6];

    float* out_att   = (float*)d_out;                 // 64*2048
    float* out_alpha = out_att + BATCH * FEATSZ;      // 64*512

    char* ws = (char*)d_ws;
    float* h            = (float*)(ws);               // 128 KB
    float* part_sc      = (float*)(ws + 131072);      // 4 x 128 KB = 512 KB
    unsigned short* wvb = (unsigned short*)(ws + 655360);  // 2 MB
    float* part         = (float*)(ws + 655360);      // 2 MB (reuses wvb after K1)

    hipLaunchKernelGGL(k_h,        dim3(8, 64),    dim3(256), 0, stream, key, wh_w, wh_b, h);
    hipLaunchKernelGGL(k_wvcvt,    dim3(4096),     dim3(256), 0, stream, wv_w, wvb);
    hipLaunchKernelGGL(k_scores,   dim3(1024),     dim3(256), 0, stream, feats, wvb, h, wv_b, wa_w, part_sc);
    hipLaunchKernelGGL(k_softmax,  dim3(64),       dim3(512), 0, stream, part_sc, out_alpha);
    hipLaunchKernelGGL(k_att_part, dim3(64, 2, 4), dim3(256), 0, stream, feats, out_alpha, part);
    hipLaunchKernelGGL(k_att_red,  dim3(128),      dim3(256), 0, stream, part, out_att);
}